// Round 6
// baseline (235.286 us; speedup 1.0000x reference)
//
#include <hip/hip_runtime.h>
#include <stdint.h>

typedef unsigned short u16;
typedef __bf16 bf16x8 __attribute__((ext_vector_type(8)));
typedef float f32x4 __attribute__((ext_vector_type(4)));
typedef unsigned short u16x8 __attribute__((ext_vector_type(8)));

#define TTOK 2048
#define DIMSZ 1024
#define NROUT 16
#define INTERSZ 512
#define BK 64
#define CHK 8    // BK/8 chunks of 8 u16 per row

__device__ __forceinline__ u16 f2bf(float f) {
    unsigned int u = __builtin_bit_cast(unsigned int, f);
    unsigned int r = u + 0x7FFFu + ((u >> 16) & 1u);
    return (u16)(r >> 16);
}

__device__ __forceinline__ void gl2lds16(const void* g, void* l) {
    __builtin_amdgcn_global_load_lds(
        (const __attribute__((address_space(1))) void*)(uintptr_t)g,
        (__attribute__((address_space(3))) void*)(uintptr_t)l,
        16, 0, 0);
}

// ---- prep_cast: pure fp32->bf16 weight cast, grid (1152, 3) ----
#define NF4A (NROUT * INTERSZ * DIMSZ / 4)   // 2,097,152 float4s (routed group)
#define CASTA_BLKS 1024                      // NF4A / 2048
__global__ __launch_bounds__(256) void prep_cast(
    const float* __restrict__ w1, const float* __restrict__ sw1,
    const float* __restrict__ w3, const float* __restrict__ sw3,
    const float* __restrict__ w2, const float* __restrict__ sw2,
    u16* __restrict__ W1b, u16* __restrict__ W3b, u16* __restrict__ W2b) {
    const int r = blockIdx.y;
    const int tid = threadIdx.x;
    const float* a; const float* b; u16* d;
    if (r == 0)      { a = w1; b = sw1; d = W1b; }
    else if (r == 1) { a = w3; b = sw3; d = W3b; }
    else             { a = w2; b = sw2; d = W2b; }
    const float4* src = (blockIdx.x < CASTA_BLKS)
                        ? (const float4*)a
                        : (const float4*)b - (size_t)CASTA_BLKS * 2048;
    ushort4* dst = (ushort4*)d;
    const size_t gbase = (size_t)blockIdx.x * 2048;
    float4 v[8];
    #pragma unroll
    for (int k = 0; k < 8; ++k)
        v[k] = src[gbase + k * 256 + tid];
    #pragma unroll
    for (int k = 0; k < 8; ++k) {
        ushort4 o;
        o.x = f2bf(v[k].x); o.y = f2bf(v[k].y);
        o.z = f2bf(v[k].z); o.w = f2bf(v[k].w);
        dst[gbase + k * 256 + tid] = o;
    }
}

// ---- prep_gate: gate + Xbf cast, one block per token ----
__global__ __launch_bounds__(256) void prep_gate(
    const float* __restrict__ x, const float* __restrict__ gw,
    int* __restrict__ topi, float2* __restrict__ topw,
    u16* __restrict__ Xbf) {
    const int tid = threadIdx.x;
    const int t = blockIdx.x;
    const int wave = tid >> 6, lane = tid & 63;
    const int d0 = tid * 4;
    float4 xv = *(const float4*)(x + (size_t)t * DIMSZ + d0);
    ushort4 o;
    o.x = f2bf(xv.x); o.y = f2bf(xv.y); o.z = f2bf(xv.z); o.w = f2bf(xv.w);
    *(ushort4*)&Xbf[(size_t)t * DIMSZ + d0] = o;

    float acc[16];
    #pragma unroll
    for (int e = 0; e < 16; ++e) {
        float4 g = *(const float4*)(gw + e * DIMSZ + d0);
        acc[e] = xv.x * g.x + xv.y * g.y + xv.z * g.z + xv.w * g.w;
    }
    #pragma unroll
    for (int off = 32; off > 0; off >>= 1) {
        #pragma unroll
        for (int e = 0; e < 16; ++e) acc[e] += __shfl_xor(acc[e], off);
    }
    __shared__ float part[4][16];
    __shared__ float sfin[16];
    if (lane < 16) part[wave][lane] = acc[lane];
    __syncthreads();
    if (wave == 0 && lane < 16) {
        float s = part[0][lane] + part[1][lane] + part[2][lane] + part[3][lane];
        sfin[lane] = 1.f / (1.f + expf(-s));
    }
    __syncthreads();
    if (tid == 0) {
        int i0 = 0; float v0 = sfin[0];
        #pragma unroll
        for (int e = 1; e < 16; ++e) { float v = sfin[e]; if (v > v0) { v0 = v; i0 = e; } }
        int i1 = -1; float v1 = -1e30f;
        #pragma unroll
        for (int e = 0; e < 16; ++e) { float v = sfin[e]; if (e != i0 && v > v1) { v1 = v; i1 = e; } }
        float inv = 1.f / (v0 + v1);
        topi[t] = i0 | (i1 << 8);
        topw[t] = make_float2(v0 * inv, v1 * inv);
    }
}

// ---- route: one block per expert; block-wide prefix sum -> ordered compact lists ----
__global__ __launch_bounds__(256) void route_kernel(
    const int* __restrict__ topi, const float2* __restrict__ topw,
    int* __restrict__ counts, int* __restrict__ tokidx, float* __restrict__ tokw) {
    const int e = blockIdx.x;
    const int tid = threadIdx.x;
    int p[8]; int m[8]; int cnt = 0;
    #pragma unroll
    for (int j = 0; j < 8; ++j) {
        int t = tid * 8 + j;
        p[j] = topi[t];
        m[j] = ((p[j] & 255) == e) || ((p[j] >> 8) == e) ? 1 : 0;
        cnt += m[j];
    }
    const int lane = tid & 63, wave = tid >> 6;
    int v = cnt;
    #pragma unroll
    for (int off = 1; off < 64; off <<= 1) {
        int u = __shfl_up(v, off);
        if (lane >= off) v += u;
    }
    __shared__ int wsum[4];
    if (lane == 63) wsum[wave] = v;
    __syncthreads();
    int wbase = 0;
    #pragma unroll
    for (int w = 0; w < 4; ++w) wbase += (w < wave) ? wsum[w] : 0;
    int base = wbase + v - cnt;
    #pragma unroll
    for (int j = 0; j < 8; ++j) {
        if (m[j]) {
            int t = tid * 8 + j;
            float2 w2 = topw[t];
            tokidx[e * TTOK + base] = t;
            tokw[e * TTOK + base] = ((p[j] & 255) == e) ? w2.x : w2.y;
            ++base;
        }
    }
    if (tid == 0) counts[e] = wsum[0] + wsum[1] + wsum[2] + wsum[3];
}

// ---- GEMM1: BM=64 BN=64 BK=64, 2-phase double-buffered LDS pipeline.
// Raw s_barrier + one vmcnt(0) per K-tile: prefetch of tile kt+1 is issued
// BEFORE computing tile kt, so its latency hides under the MFMA phase.
__global__ __launch_bounds__(256) void gemm1s(
    const u16* __restrict__ Xbf, const u16* __restrict__ W1b,
    const u16* __restrict__ W3b, const int* __restrict__ counts,
    const int* __restrict__ tokidx, const float* __restrict__ tokw,
    u16* __restrict__ Hc, u16* __restrict__ Hs) {
    const int e = blockIdx.z;
    const int cnt = (e < NROUT) ? counts[e] : TTOK;
    const int m0 = blockIdx.y * 64;
    if (m0 >= cnt) return;
    const int n0 = blockIdx.x * 64;
    __shared__ u16 As[2][64 * BK], B1s[2][64 * BK], B3s[2][64 * BK];
    const u16* B1 = W1b + ((size_t)e * INTERSZ + n0) * DIMSZ;
    const u16* B3 = W3b + ((size_t)e * INTERSZ + n0) * DIMSZ;
    const int tid = threadIdx.x;

    int row[2], cgs[2]; size_t arow[2];
    #pragma unroll
    for (int i = 0; i < 2; ++i) {
        int c = tid + i * 256;
        row[i] = c >> 3;
        cgs[i] = ((c & 7) ^ (row[i] & 7)) * 8;
        int slot = m0 + row[i];
        int g;
        if (e < NROUT) g = (slot < cnt) ? tokidx[e * TTOK + slot] : 0;
        else           g = slot;
        arow[i] = (size_t)g * DIMSZ;
    }
    f32x4 acc1[2][2] = {}; f32x4 acc3[2][2] = {};
    const int wave = tid >> 6, lane = tid & 63;
    const int wm = (wave >> 1) * 32, wn = (wave & 1) * 32;
    const int lr = lane & 15, lq = lane >> 4;
    const int NKT = DIMSZ / BK;  // 16

#define STG1(kt, h) { \
    const int k0_ = (kt) * BK; \
    _Pragma("unroll") \
    for (int i = 0; i < 2; ++i) { \
        int c = tid + i * 256; \
        gl2lds16(Xbf + arow[i] + k0_ + cgs[i], &As[h][c * 8]); \
        size_t boff = (size_t)row[i] * DIMSZ + k0_ + cgs[i]; \
        gl2lds16(B1 + boff, &B1s[h][c * 8]); \
        gl2lds16(B3 + boff, &B3s[h][c * 8]); \
    } }

    STG1(0, 0);
    asm volatile("s_waitcnt vmcnt(0)" ::: "memory");
    __builtin_amdgcn_s_barrier();

    #pragma unroll 2
    for (int kt = 0; kt < NKT; ++kt) {
        const int cur = kt & 1;
        if (kt + 1 < NKT) STG1(kt + 1, cur ^ 1);
        __builtin_amdgcn_s_setprio(1);
        #pragma unroll
        for (int ks = 0; ks < 2; ++ks) {
            bf16x8 af[2], b1f[2], b3f[2];
            const int g = ks * 4 + lq;
            #pragma unroll
            for (int mt = 0; mt < 2; ++mt) {
                int m = wm + mt * 16 + lr;
                af[mt] = *(const bf16x8*)&As[cur][(m * CHK + (g ^ (m & 7))) * 8];
            }
            #pragma unroll
            for (int nt = 0; nt < 2; ++nt) {
                int n = wn + nt * 16 + lr;
                int ch = (n * CHK + (g ^ (n & 7))) * 8;
                b1f[nt] = *(const bf16x8*)&B1s[cur][ch];
                b3f[nt] = *(const bf16x8*)&B3s[cur][ch];
            }
            #pragma unroll
            for (int mt = 0; mt < 2; ++mt) {
                #pragma unroll
                for (int nt = 0; nt < 2; ++nt) {
                    acc1[mt][nt] = __builtin_amdgcn_mfma_f32_16x16x32_bf16(af[mt], b1f[nt], acc1[mt][nt], 0, 0, 0);
                    acc3[mt][nt] = __builtin_amdgcn_mfma_f32_16x16x32_bf16(af[mt], b3f[nt], acc3[mt][nt], 0, 0, 0);
                }
            }
        }
        __builtin_amdgcn_s_setprio(0);
        asm volatile("s_waitcnt vmcnt(0)" ::: "memory");
        __builtin_amdgcn_s_barrier();
    }
#undef STG1
    #pragma unroll
    for (int mt = 0; mt < 2; ++mt) {
        #pragma unroll
        for (int nt = 0; nt < 2; ++nt) {
            #pragma unroll
            for (int r = 0; r < 4; ++r) {
                int m = wm + mt * 16 + lq * 4 + r;
                int n = wn + nt * 16 + lr;
                int slot = m0 + m;
                bool valid = slot < cnt;
                float h1 = acc1[mt][nt][r], h3 = acc3[mt][nt][r];
                float hv = 0.f;
                if (valid) {
                    float tw = (e < NROUT) ? tokw[e * TTOK + slot] : 1.0f;
                    hv = h1 / (1.f + __expf(-h1)) * h3 * tw;
                }
                if (e < NROUT)
                    Hc[((size_t)e * TTOK + slot) * INTERSZ + n0 + n] = f2bf(hv);
                else
                    Hs[(size_t)slot * DIMSZ + (e - NROUT) * INTERSZ + n0 + n] = f2bf(hv);
            }
        }
    }
}

// ---- GEMM2 routed: BM=64 BN=64 BK=64, K=512, 2-phase pipeline, plain stores.
__global__ __launch_bounds__(256) void gemm2rt(
    const u16* __restrict__ Hc, const u16* __restrict__ W2b,
    const int* __restrict__ counts, const int* __restrict__ tokidx,
    const int* __restrict__ topi,
    float* __restrict__ bufA, float* __restrict__ bufB) {
    const int e = blockIdx.z;
    const int cnt = counts[e];
    const int m0 = blockIdx.y * 64;
    if (m0 >= cnt) return;
    const int n0 = blockIdx.x * 64;
    __shared__ u16 As[2][64 * BK], Bs[2][64 * BK];
    const u16* A0 = Hc + ((size_t)e * TTOK + m0) * INTERSZ;
    const u16* B0 = W2b + ((size_t)e * DIMSZ + n0) * INTERSZ;
    const int tid = threadIdx.x;
    const int wave = tid >> 6, lane = tid & 63;
    const int wm = (wave >> 1) * 32, wn = (wave & 1) * 32;
    const int lr = lane & 15, lq = lane >> 4;

    int row[2], cgs[2];
    #pragma unroll
    for (int i = 0; i < 2; ++i) {
        int c = tid + i * 256;
        row[i] = c >> 3;
        cgs[i] = ((c & 7) ^ (row[i] & 7)) * 8;
    }
    f32x4 acc[2][2] = {};
    const int NKT = INTERSZ / BK;  // 8

#define STG2(kt, h) { \
    const int k0_ = (kt) * BK; \
    _Pragma("unroll") \
    for (int i = 0; i < 2; ++i) { \
        int c = tid + i * 256; \
        gl2lds16(A0 + (size_t)row[i] * INTERSZ + k0_ + cgs[i], &As[h][c * 8]); \
        gl2lds16(B0 + (size_t)row[i] * INTERSZ + k0_ + cgs[i], &Bs[h][c * 8]); \
    } }

    STG2(0, 0);
    asm volatile("s_waitcnt vmcnt(0)" ::: "memory");
    __builtin_amdgcn_s_barrier();

    #pragma unroll 2
    for (int kt = 0; kt < NKT; ++kt) {
        const int cur = kt & 1;
        if (kt + 1 < NKT) STG2(kt + 1, cur ^ 1);
        __builtin_amdgcn_s_setprio(1);
        #pragma unroll
        for (int ks = 0; ks < 2; ++ks) {
            bf16x8 af[2], bfr[2];
            const int g = ks * 4 + lq;
            #pragma unroll
            for (int mt = 0; mt < 2; ++mt) {
                int m = wm + mt * 16 + lr;
                af[mt] = *(const bf16x8*)&As[cur][(m * CHK + (g ^ (m & 7))) * 8];
            }
            #pragma unroll
            for (int nt = 0; nt < 2; ++nt) {
                int n = wn + nt * 16 + lr;
                bfr[nt] = *(const bf16x8*)&Bs[cur][(n * CHK + (g ^ (n & 7))) * 8];
            }
            #pragma unroll
            for (int mt = 0; mt < 2; ++mt) {
                #pragma unroll
                for (int nt = 0; nt < 2; ++nt) {
                    acc[mt][nt] = __builtin_amdgcn_mfma_f32_16x16x32_bf16(af[mt], bfr[nt], acc[mt][nt], 0, 0, 0);
                }
            }
        }
        __builtin_amdgcn_s_setprio(0);
        asm volatile("s_waitcnt vmcnt(0)" ::: "memory");
        __builtin_amdgcn_s_barrier();
    }
#undef STG2
    #pragma unroll
    for (int mt = 0; mt < 2; ++mt) {
        #pragma unroll
        for (int r = 0; r < 4; ++r) {
            int m = wm + mt * 16 + lq * 4 + r;
            int slot = m0 + m;
            if (slot < cnt) {
                int t = tokidx[e * TTOK + slot];
                float* db = ((topi[t] & 255) == e) ? bufA : bufB;
                #pragma unroll
                for (int nt = 0; nt < 2; ++nt) {
                    int n = wn + nt * 16 + lr;
                    db[(size_t)t * DIMSZ + n0 + n] = acc[mt][nt][r];
                }
            }
        }
    }
}

// ---- GEMM2 shared: BM=64 BN=64 BK=64, K=1024, 2-phase; epilogue combines
// shared acc + bufA + bufB and writes out once.
__global__ __launch_bounds__(256) void gemm2sh(
    const u16* __restrict__ Hs, const u16* __restrict__ W2sb,
    const float* __restrict__ bufA, const float* __restrict__ bufB,
    float* __restrict__ out) {
    const int m0 = blockIdx.y * 64;
    const int n0 = blockIdx.x * 64;
    __shared__ u16 As[2][64 * BK], Bs[2][64 * BK];
    const u16* A0 = Hs + (size_t)m0 * DIMSZ;
    const u16* B0 = W2sb + (size_t)n0 * DIMSZ;
    const int tid = threadIdx.x;
    const int wave = tid >> 6, lane = tid & 63;
    const int wm = (wave >> 1) * 32, wn = (wave & 1) * 32;
    const int lr = lane & 15, lq = lane >> 4;

    int row[2], cgs[2];
    #pragma unroll
    for (int i = 0; i < 2; ++i) {
        int c = tid + i * 256;
        row[i] = c >> 3;
        cgs[i] = ((c & 7) ^ (row[i] & 7)) * 8;
    }
    f32x4 acc[2][2] = {};
    const int NKT = DIMSZ / BK;  // 16

#define STG3(kt, h) { \
    const int k0_ = (kt) * BK; \
    _Pragma("unroll") \
    for (int i = 0; i < 2; ++i) { \
        int c = tid + i * 256; \
        gl2lds16(A0 + (size_t)row[i] * DIMSZ + k0_ + cgs[i], &As[h][c * 8]); \
        gl2lds16(B0 + (size_t)row[i] * DIMSZ + k0_ + cgs[i], &Bs[h][c * 8]); \
    } }

    STG3(0, 0);
    asm volatile("s_waitcnt vmcnt(0)" ::: "memory");
    __builtin_amdgcn_s_barrier();

    #pragma unroll 2
    for (int kt = 0; kt < NKT; ++kt) {
        const int cur = kt & 1;
        if (kt + 1 < NKT) STG3(kt + 1, cur ^ 1);
        __builtin_amdgcn_s_setprio(1);
        #pragma unroll
        for (int ks = 0; ks < 2; ++ks) {
            bf16x8 af[2], bfr[2];
            const int g = ks * 4 + lq;
            #pragma unroll
            for (int mt = 0; mt < 2; ++mt) {
                int m = wm + mt * 16 + lr;
                af[mt] = *(const bf16x8*)&As[cur][(m * CHK + (g ^ (m & 7))) * 8];
            }
            #pragma unroll
            for (int nt = 0; nt < 2; ++nt) {
                int n = wn + nt * 16 + lr;
                bfr[nt] = *(const bf16x8*)&Bs[cur][(n * CHK + (g ^ (n & 7))) * 8];
            }
            #pragma unroll
            for (int mt = 0; mt < 2; ++mt) {
                #pragma unroll
                for (int nt = 0; nt < 2; ++nt) {
                    acc[mt][nt] = __builtin_amdgcn_mfma_f32_16x16x32_bf16(af[mt], bfr[nt], acc[mt][nt], 0, 0, 0);
                }
            }
        }
        __builtin_amdgcn_s_setprio(0);
        asm volatile("s_waitcnt vmcnt(0)" ::: "memory");
        __builtin_amdgcn_s_barrier();
    }
#undef STG3
    #pragma unroll
    for (int mt = 0; mt < 2; ++mt) {
        #pragma unroll
        for (int r = 0; r < 4; ++r) {
            int t = m0 + wm + mt * 16 + lq * 4 + r;
            #pragma unroll
            for (int nt = 0; nt < 2; ++nt) {
                int n = wn + nt * 16 + lr;
                size_t idx = (size_t)t * DIMSZ + n0 + n;
                out[idx] = acc[mt][nt][r] + bufA[idx] + bufB[idx];
            }
        }
    }
}

extern "C" void kernel_launch(void* const* d_in, const int* in_sizes, int n_in,
                              void* d_out, int out_size, void* d_ws, size_t ws_size,
                              hipStream_t stream) {
    const float* x      = (const float*)d_in[0];
    const float* gate_w = (const float*)d_in[1];
    const float* w1     = (const float*)d_in[2];
    const float* w2     = (const float*)d_in[3];
    const float* w3     = (const float*)d_in[4];
    const float* sw1    = (const float*)d_in[5];
    const float* sw2    = (const float*)d_in[6];
    const float* sw3    = (const float*)d_in[7];
    float* out = (float*)d_out;

    char* ws = (char*)d_ws;
    const size_t SZ_W   = (size_t)(NROUT + 2) * INTERSZ * DIMSZ * 2;
    const size_t SZ_XBF = (size_t)TTOK * DIMSZ * 2;
    u16*   W1b    = (u16*)(ws);
    u16*   W3b    = (u16*)(ws + SZ_W);
    u16*   W2all  = (u16*)(ws + 2 * SZ_W);
    u16*   Xbf    = (u16*)(ws + 3 * SZ_W);
    char*  route  = ws + 3 * SZ_W + SZ_XBF;
    int*   counts = (int*)route;
    int*   topi   = (int*)(route + 256);
    float2* topw  = (float2*)(route + 256 + TTOK * 4);
    int*   tokidx = (int*)(route + 256 + TTOK * 12);
    float* tokw   = (float*)(route + 256 + TTOK * 12 + 16 * TTOK * 4);
    char*  hbuf   = route + 256 + TTOK * 12 + 2 * (size_t)16 * TTOK * 4;
    u16*   Hc     = (u16*)hbuf;                                        // [16][2048][512]
    u16*   Hs     = (u16*)(hbuf + (size_t)NROUT * TTOK * INTERSZ * 2); // [2048][1024]
    char*  bufs   = hbuf + (size_t)NROUT * TTOK * INTERSZ * 2 + (size_t)TTOK * DIMSZ * 2;
    float* bufA   = (float*)bufs;                                      // [2048][1024] fp32
    float* bufB   = (float*)(bufs + (size_t)TTOK * DIMSZ * 4);
    u16*   W2sb   = W2all + (size_t)NROUT * DIMSZ * INTERSZ;

    prep_cast<<<dim3(1152, 3), 256, 0, stream>>>(
        w1, sw1, w3, sw3, w2, sw2, W1b, W3b, W2all);
    prep_gate<<<dim3(2048), 256, 0, stream>>>(x, gate_w, topi, topw, Xbf);
    route_kernel<<<NROUT, 256, 0, stream>>>(topi, topw, counts, tokidx, tokw);
    gemm1s<<<dim3(INTERSZ / 64, TTOK / 64, NROUT + 2), 256, 0, stream>>>(
        Xbf, W1b, W3b, counts, tokidx, tokw, Hc, Hs);
    gemm2rt<<<dim3(DIMSZ / 64, TTOK / 64, NROUT), 256, 0, stream>>>(
        Hc, W2all, counts, tokidx, topi, bufA, bufB);
    gemm2sh<<<dim3(DIMSZ / 64, TTOK / 64), 256, 0, stream>>>(
        Hs, W2sb, bufA, bufB, out);
}